// Round 5
// baseline (347.296 us; speedup 1.0000x reference)
//
#include <hip/hip_runtime.h>
#include <hip/hip_fp16.h>

#define N_NODES 50000
#define N_EDGES 600000
#define N_GRAPHS 64
#define HID 128
#define OUT_C 32

#define SCAN_BLK 256
#define N_SCAN_BLOCKS ((N_NODES + SCAN_BLK - 1) / SCAN_BLK)   // 196

typedef __attribute__((ext_vector_type(8))) short short8;
typedef __attribute__((ext_vector_type(8))) unsigned short ushort8;
typedef __attribute__((ext_vector_type(4))) float f32x4;

// ---------------- weight prep: split-bf16 planes, n-major (B^T layout, contiguous k)
__global__ void build_w_bf16(const float* __restrict__ Wl, const float* __restrict__ Wr,
                             unsigned short* __restrict__ Whn, unsigned short* __restrict__ Wln) {
    int idx = blockIdx.x * 256 + threadIdx.x;   // 0..32767
    int n = idx >> 8, k = idx & 255;
    float a = (k < 128) ? Wl[n * 128 + k] : Wr[n * 128 + (k - 128)];
    unsigned int u = __float_as_uint(a);
    float hf = __uint_as_float(u & 0xFFFF0000u);
    float lf = a - hf;                 // exact (low mantissa bits)
    Whn[idx] = (unsigned short)(u >> 16);
    Wln[idx] = (unsigned short)(__float_as_uint(lf) >> 16);
}

// ---------------- fp32 -> fp16 cast (vectorized)
__global__ void cast_f16(const float* __restrict__ in, __half* __restrict__ out, int n) {
    int i = (blockIdx.x * 256 + threadIdx.x) * 4;
    if (i < n) {
        float4 v = *(const float4*)(in + i);
        __half2 a = __floats2half2_rn(v.x, v.y);
        __half2 b = __floats2half2_rn(v.z, v.w);
        uint2 st;
        st.x = *(const unsigned int*)&a;
        st.y = *(const unsigned int*)&b;
        *(uint2*)(out + i) = st;
    }
}

// ---------------- CSR build
__global__ void deg_kernel(const int* __restrict__ dst, int* __restrict__ deg, int E) {
    int e = blockIdx.x * 256 + threadIdx.x;
    if (e < E) atomicAdd(&deg[dst[e]], 1);
}

__global__ __launch_bounds__(SCAN_BLK) void scan_blocksum(
    const int* __restrict__ deg, int* __restrict__ bsum) {
    __shared__ int s[SCAN_BLK];
    int i = blockIdx.x * SCAN_BLK + threadIdx.x;
    s[threadIdx.x] = (i < N_NODES) ? deg[i] : 0;
    __syncthreads();
    for (int off = SCAN_BLK / 2; off > 0; off >>= 1) {
        if (threadIdx.x < off) s[threadIdx.x] += s[threadIdx.x + off];
        __syncthreads();
    }
    if (threadIdx.x == 0) bsum[blockIdx.x] = s[0];
}

__global__ __launch_bounds__(256) void scan_boff(
    const int* __restrict__ bsum, int* __restrict__ boff, int* __restrict__ rowptr) {
    __shared__ int s[256];
    int t = threadIdx.x;
    int v = (t < N_SCAN_BLOCKS) ? bsum[t] : 0;
    s[t] = v;
    __syncthreads();
    for (int off = 1; off < 256; off <<= 1) {
        int u = (t >= off) ? s[t - off] : 0;
        __syncthreads();
        s[t] += u;
        __syncthreads();
    }
    if (t < N_SCAN_BLOCKS) boff[t] = s[t] - v;
    if (t == N_SCAN_BLOCKS - 1) rowptr[N_NODES] = s[t];
}

__global__ __launch_bounds__(SCAN_BLK) void scan_emit(
    const int* __restrict__ deg, const int* __restrict__ boff,
    int* __restrict__ rowptr, float* __restrict__ invdeg) {
    __shared__ int s[SCAN_BLK];
    int i = blockIdx.x * SCAN_BLK + threadIdx.x;
    int t = threadIdx.x;
    int v = (i < N_NODES) ? deg[i] : 0;
    s[t] = v;
    __syncthreads();
    for (int off = 1; off < SCAN_BLK; off <<= 1) {
        int u = (t >= off) ? s[t - off] : 0;
        __syncthreads();
        s[t] += u;
        __syncthreads();
    }
    if (i < N_NODES) {
        rowptr[i] = boff[blockIdx.x] + s[t] - v;
        invdeg[i] = 1.0f / fmaxf((float)v, 1.0f);
    }
}

__global__ void fill_kernel(const int* __restrict__ src, const int* __restrict__ dst,
                            const int* __restrict__ rowptr, int* __restrict__ cursor,
                            int* __restrict__ eidx, int E) {
    int e = blockIdx.x * 256 + threadIdx.x;
    if (e < E) {
        int d = dst[e];
        int pos = atomicAdd(&cursor[d], 1);
        eidx[rowptr[d] + pos] = src[e];
    }
}

// ---------------- fp16 gather-aggregate: one wave per node, lane handles 2 channels (4 B).
__global__ __launch_bounds__(256) void aggregate_f16(
    const __half* __restrict__ feat16, const int* __restrict__ rowptr,
    const int* __restrict__ eidx, const float* __restrict__ invdeg,
    float* __restrict__ mean) {
    const int node = blockIdx.x * 4 + (threadIdx.x >> 6);
    if (node >= N_NODES) return;
    const int lane = threadIdx.x & 63;
    const int beg = rowptr[node];
    const int end = rowptr[node + 1];
    float2 acc = make_float2(0.f, 0.f);
    int i = beg;
    int s_next = (i < end) ? eidx[i] : 0;
    for (; i < end; ++i) {
        const int s = s_next;
        if (i + 1 < end) s_next = eidx[i + 1];
        const __half2 v = *(const __half2*)(feat16 + (size_t)s * 128 + lane * 2);
        const float2 f = __half22float2(v);
        acc.x += f.x;
        acc.y += f.y;
    }
    const float sc = invdeg[node];
    acc.x *= sc;
    acc.y *= sc;
    *(float2*)(mean + (size_t)node * 128 + lane * 2) = acc;
}

// ---------------- split-bf16 MFMA SAGE GEMM (M=50000, N=128, K=256)
// C = Ah@Bh + Ah@Bl + Al@Bh  (lo*lo dropped, ~2^-16 relative)
#define GBM 64
#define GBK 32
#define ASTR 48   // ushorts per LDS row (32 data + 16 pad; 96 B, 16B-aligned)
#define BSTR 48

__global__ __launch_bounds__(256) void sage_gemm_mfma(
    const float* __restrict__ mean, const float* __restrict__ feat,
    const unsigned short* __restrict__ Whn, const unsigned short* __restrict__ Wln,
    const float* __restrict__ bias, float* __restrict__ out,
    __half* __restrict__ out16, int M) {
    __shared__ __align__(16) unsigned short Ah[GBM][ASTR];
    __shared__ __align__(16) unsigned short Al[GBM][ASTR];
    __shared__ __align__(16) unsigned short Bh[128][BSTR];
    __shared__ __align__(16) unsigned short Bl[128][BSTR];

    const int tid = threadIdx.x;
    const int wave = tid >> 6;
    const int lane = tid & 63;
    const int l15 = lane & 15;
    const int quad = lane >> 4;
    const int row0 = blockIdx.x * GBM;

    f32x4 acc[8];
#pragma unroll
    for (int t = 0; t < 8; ++t) acc[t] = (f32x4){0.f, 0.f, 0.f, 0.f};

    const int ar = tid >> 2;          // A stage: row 0..63
    const int ac = (tid & 3) * 8;     // A stage: k offset {0,8,16,24}

    for (int k0 = 0; k0 < 256; k0 += GBK) {
        // ---- stage A: fp32 -> bf16 hi/lo planes
        {
            int gi = row0 + ar;
            float va[8];
            if (gi < M) {
                const float* p = (k0 < 128) ? (mean + (size_t)gi * 128 + k0 + ac)
                                            : (feat + (size_t)gi * 128 + (k0 - 128) + ac);
                float4 v0 = *(const float4*)p;
                float4 v1 = *(const float4*)(p + 4);
                va[0] = v0.x; va[1] = v0.y; va[2] = v0.z; va[3] = v0.w;
                va[4] = v1.x; va[5] = v1.y; va[6] = v1.z; va[7] = v1.w;
            } else {
#pragma unroll
                for (int i = 0; i < 8; ++i) va[i] = 0.f;
            }
            ushort8 h, l;
#pragma unroll
            for (int i = 0; i < 8; ++i) {
                unsigned int u = __float_as_uint(va[i]);
                float hf = __uint_as_float(u & 0xFFFF0000u);
                float lf = va[i] - hf;           // exact residual
                h[i] = (unsigned short)(u >> 16);
                l[i] = (unsigned short)(__float_as_uint(lf) >> 16);
            }
            *(ushort8*)&Ah[ar][ac] = h;
            *(ushort8*)&Al[ar][ac] = l;
        }
        // ---- stage B: copy pre-split ushort planes (16B chunks)
#pragma unroll
        for (int i = 0; i < 2; ++i) {
            int id = tid + i * 256;              // 0..511
            int n = id >> 2;
            int kc = (id & 3) * 8;
            *(ushort8*)&Bh[n][kc] = *(const ushort8*)(Whn + (size_t)n * 256 + k0 + kc);
            *(ushort8*)&Bl[n][kc] = *(const ushort8*)(Wln + (size_t)n * 256 + k0 + kc);
        }
        __syncthreads();

        const short8 a_h = *(const short8*)&Ah[wave * 16 + l15][quad * 8];
        const short8 a_l = *(const short8*)&Al[wave * 16 + l15][quad * 8];
#pragma unroll
        for (int t = 0; t < 8; ++t) {
            const short8 b_h = *(const short8*)&Bh[t * 16 + l15][quad * 8];
            const short8 b_l = *(const short8*)&Bl[t * 16 + l15][quad * 8];
            acc[t] = __builtin_amdgcn_mfma_f32_16x16x32_bf16(a_h, b_h, acc[t], 0, 0, 0);
            acc[t] = __builtin_amdgcn_mfma_f32_16x16x32_bf16(a_h, b_l, acc[t], 0, 0, 0);
            acc[t] = __builtin_amdgcn_mfma_f32_16x16x32_bf16(a_l, b_h, acc[t], 0, 0, 0);
        }
        __syncthreads();
    }

    // epilogue: row = row0 + wave*16 + quad*4 + r, col = t*16 + l15
#pragma unroll
    for (int r = 0; r < 4; ++r) {
        int gi = row0 + wave * 16 + quad * 4 + r;
        if (gi < M) {
#pragma unroll
            for (int t = 0; t < 8; ++t) {
                int col = t * 16 + l15;
                float v = fmaxf(acc[t][r] + bias[col], 0.f);
                out[(size_t)gi * 128 + col] = v;
                if (out16) out16[(size_t)gi * 128 + col] = __float2half(v);
            }
        }
    }
}

// ---------------- pooling: batch is sorted; run-length accumulate, flush on change
#define POOL_CHUNK 128
__global__ void pool_kernel(const float* __restrict__ h, const int* __restrict__ batch,
                            float* __restrict__ pooled, float* __restrict__ cntf, int N) {
    int c = threadIdx.x;               // 0..127
    int n0 = blockIdx.x * POOL_CHUNK;
    int n1 = min(n0 + POOL_CHUNK, N);
    if (n0 >= N) return;
    float run = 0.0f;
    float runc = 0.0f;
    int curg = batch[n0];
    for (int n = n0; n < n1; ++n) {
        int g = batch[n];
        if (g != curg) {
            atomicAdd(&pooled[curg * 128 + c], run);
            if (c == 0) atomicAdd(&cntf[curg], runc);
            run = 0.0f; runc = 0.0f; curg = g;
        }
        run += h[(size_t)n * 128 + c];
        runc += 1.0f;
    }
    atomicAdd(&pooled[curg * 128 + c], run);
    if (c == 0) atomicAdd(&cntf[curg], runc);
}

// ---------------- final linear
__global__ void final_kernel(const float* __restrict__ pooled, const float* __restrict__ cntf,
                             const float* __restrict__ Wlin, const float* __restrict__ blin,
                             float* __restrict__ out) {
    int g = blockIdx.x;
    int j = threadIdx.x;               // 0..31
    float inv = 1.0f / fmaxf(cntf[g], 1.0f);
    float sum = blin[j];
    const float* prow = pooled + g * 128;
    const float* wrow = Wlin + j * 128;
    for (int c = 0; c < 128; ++c) sum += prow[c] * inv * wrow[c];
    out[g * 32 + j] = sum;
}

extern "C" void kernel_launch(void* const* d_in, const int* in_sizes, int n_in,
                              void* d_out, int out_size, void* d_ws, size_t ws_size,
                              hipStream_t stream) {
    const float* x    = (const float*)d_in[0];
    const int*   src  = (const int*)d_in[1];
    const int*   dst  = ((const int*)d_in[1]) + N_EDGES;
    const int*   batch= (const int*)d_in[2];
    const float* W1l  = (const float*)d_in[3];
    const float* b1   = (const float*)d_in[4];
    const float* W1r  = (const float*)d_in[5];
    const float* W2l  = (const float*)d_in[6];
    const float* b2   = (const float*)d_in[7];
    const float* W2r  = (const float*)d_in[8];
    const float* Wlin = (const float*)d_in[9];
    const float* blin = (const float*)d_in[10];
    float* out = (float*)d_out;

    float* ws      = (float*)d_ws;
    float* mean    = ws;                       // 6,400,000 f
    float* h1      = mean + 6400000;           // 6,400,000 f
    float* h2      = h1 + 6400000;             // 6,400,000 f
    __half* xh     = (__half*)(h2 + 6400000);  // 6,400,000 h (fp16 gather table; reused as h1h)
    float* pooled  = (float*)(xh + 6400000);   // 8,192 f
    float* cntf    = pooled + N_GRAPHS * 128;  // 64 f
    float* invdeg  = cntf + 64;                // 50,000 f
    unsigned short* Whn1 = (unsigned short*)(invdeg + N_NODES);  // 32,768 us
    unsigned short* Wln1 = Whn1 + 32768;
    unsigned short* Whn2 = Wln1 + 32768;
    unsigned short* Wln2 = Whn2 + 32768;
    int*   degi    = (int*)(Wln2 + 32768);     // 50,000 i
    int*   rowptr  = degi + N_NODES;           // 50,001 i
    int*   cursor  = rowptr + N_NODES + 1;     // 50,000 i
    int*   eidx    = cursor + N_NODES;         // 600,000 i
    int*   bsum    = eidx + N_EDGES;           // 196 i
    int*   boff    = bsum + N_SCAN_BLOCKS;     // 196 i

    // zero accumulated-into scratch (ws is re-poisoned before every call)
    hipMemsetAsync(degi, 0, (size_t)N_NODES * sizeof(int), stream);
    hipMemsetAsync(cursor, 0, (size_t)N_NODES * sizeof(int), stream);
    hipMemsetAsync(pooled, 0, (size_t)(N_GRAPHS * 128 + N_GRAPHS) * sizeof(float), stream);

    // weight prep + fp16 cast of x (independent of CSR build)
    build_w_bf16<<<128, 256, 0, stream>>>(W1l, W1r, Whn1, Wln1);
    build_w_bf16<<<128, 256, 0, stream>>>(W2l, W2r, Whn2, Wln2);
    cast_f16<<<(N_NODES * 128 / 4 + 255) / 256, 256, 0, stream>>>(x, xh, N_NODES * 128);

    // CSR build: coalesced 3-phase scan
    deg_kernel<<<(N_EDGES + 255) / 256, 256, 0, stream>>>(dst, degi, N_EDGES);
    scan_blocksum<<<N_SCAN_BLOCKS, SCAN_BLK, 0, stream>>>(degi, bsum);
    scan_boff<<<1, 256, 0, stream>>>(bsum, boff, rowptr);
    scan_emit<<<N_SCAN_BLOCKS, SCAN_BLK, 0, stream>>>(degi, boff, rowptr, invdeg);
    fill_kernel<<<(N_EDGES + 255) / 256, 256, 0, stream>>>(src, dst, rowptr, cursor, eidx, N_EDGES);

    const int gemm_grid = (N_NODES + GBM - 1) / GBM;   // 782

    // layer 1: fp16 gather + GEMM (epilogue also emits fp16 h1 into xh for layer 2)
    aggregate_f16<<<(N_NODES + 3) / 4, 256, 0, stream>>>(xh, rowptr, eidx, invdeg, mean);
    sage_gemm_mfma<<<gemm_grid, 256, 0, stream>>>(mean, x, Whn1, Wln1, b1, h1, xh, N_NODES);

    // layer 2
    aggregate_f16<<<(N_NODES + 3) / 4, 256, 0, stream>>>(xh, rowptr, eidx, invdeg, mean);
    sage_gemm_mfma<<<gemm_grid, 256, 0, stream>>>(mean, h1, Whn2, Wln2, b2, h2, (\
        __half*)nullptr, N_NODES);

    // pool + final linear
    pool_kernel<<<(N_NODES + POOL_CHUNK - 1) / POOL_CHUNK, 128, 0, stream>>>(h2, batch, pooled, cntf, N_NODES);
    final_kernel<<<N_GRAPHS, 32, 0, stream>>>(pooled, cntf, Wlin, blin, out);
}

// Round 6
// 305.483 us; speedup vs baseline: 1.1369x; 1.1369x over previous
//
#include <hip/hip_runtime.h>
#include <hip/hip_fp16.h>

#define N_NODES 50000
#define N_EDGES 600000
#define N_GRAPHS 64
#define HID 128
#define OUT_C 32

#define SCAN_BLK 256
#define N_SCAN_BLOCKS ((N_NODES + SCAN_BLK - 1) / SCAN_BLK)   // 196

typedef __attribute__((ext_vector_type(8))) short short8;
typedef __attribute__((ext_vector_type(8))) unsigned short ushort8;
typedef __attribute__((ext_vector_type(4))) float f32x4;

// ---------------- weight prep: split-bf16 planes, n-major (B^T layout, contiguous k)
__global__ void build_w_bf16(const float* __restrict__ Wl, const float* __restrict__ Wr,
                             unsigned short* __restrict__ Whn, unsigned short* __restrict__ Wln) {
    int idx = blockIdx.x * 256 + threadIdx.x;   // 0..32767
    int n = idx >> 8, k = idx & 255;
    float a = (k < 128) ? Wl[n * 128 + k] : Wr[n * 128 + (k - 128)];
    unsigned int u = __float_as_uint(a);
    float hf = __uint_as_float(u & 0xFFFF0000u);
    float lf = a - hf;                 // exact (low mantissa bits)
    Whn[idx] = (unsigned short)(u >> 16);
    Wln[idx] = (unsigned short)(__float_as_uint(lf) >> 16);
}

// ---------------- fp32 -> fp16 cast (vectorized)
__global__ void cast_f16(const float* __restrict__ in, __half* __restrict__ out, int n) {
    int i = (blockIdx.x * 256 + threadIdx.x) * 4;
    if (i < n) {
        float4 v = *(const float4*)(in + i);
        __half2 a = __floats2half2_rn(v.x, v.y);
        __half2 b = __floats2half2_rn(v.z, v.w);
        uint2 st;
        st.x = *(const unsigned int*)&a;
        st.y = *(const unsigned int*)&b;
        *(uint2*)(out + i) = st;
    }
}

// ---------------- CSR build
__global__ void deg_kernel(const int* __restrict__ dst, int* __restrict__ deg, int E) {
    int e = blockIdx.x * 256 + threadIdx.x;
    if (e < E) atomicAdd(&deg[dst[e]], 1);
}

__global__ __launch_bounds__(SCAN_BLK) void scan_blocksum(
    const int* __restrict__ deg, int* __restrict__ bsum) {
    __shared__ int s[SCAN_BLK];
    int i = blockIdx.x * SCAN_BLK + threadIdx.x;
    s[threadIdx.x] = (i < N_NODES) ? deg[i] : 0;
    __syncthreads();
    for (int off = SCAN_BLK / 2; off > 0; off >>= 1) {
        if (threadIdx.x < off) s[threadIdx.x] += s[threadIdx.x + off];
        __syncthreads();
    }
    if (threadIdx.x == 0) bsum[blockIdx.x] = s[0];
}

__global__ __launch_bounds__(256) void scan_boff(
    const int* __restrict__ bsum, int* __restrict__ boff, int* __restrict__ rowptr) {
    __shared__ int s[256];
    int t = threadIdx.x;
    int v = (t < N_SCAN_BLOCKS) ? bsum[t] : 0;
    s[t] = v;
    __syncthreads();
    for (int off = 1; off < 256; off <<= 1) {
        int u = (t >= off) ? s[t - off] : 0;
        __syncthreads();
        s[t] += u;
        __syncthreads();
    }
    if (t < N_SCAN_BLOCKS) boff[t] = s[t] - v;
    if (t == N_SCAN_BLOCKS - 1) rowptr[N_NODES] = s[t];
}

__global__ __launch_bounds__(SCAN_BLK) void scan_emit(
    const int* __restrict__ deg, const int* __restrict__ boff,
    int* __restrict__ rowptr, float* __restrict__ invdeg) {
    __shared__ int s[SCAN_BLK];
    int i = blockIdx.x * SCAN_BLK + threadIdx.x;
    int t = threadIdx.x;
    int v = (i < N_NODES) ? deg[i] : 0;
    s[t] = v;
    __syncthreads();
    for (int off = 1; off < SCAN_BLK; off <<= 1) {
        int u = (t >= off) ? s[t - off] : 0;
        __syncthreads();
        s[t] += u;
        __syncthreads();
    }
    if (i < N_NODES) {
        rowptr[i] = boff[blockIdx.x] + s[t] - v;
        invdeg[i] = 1.0f / fmaxf((float)v, 1.0f);
    }
}

__global__ void fill_kernel(const int* __restrict__ src, const int* __restrict__ dst,
                            const int* __restrict__ rowptr, int* __restrict__ cursor,
                            int* __restrict__ eidx, int E) {
    int e = blockIdx.x * 256 + threadIdx.x;
    if (e < E) {
        int d = dst[e];
        int pos = atomicAdd(&cursor[d], 1);
        eidx[rowptr[d] + pos] = src[e];
    }
}

// ---------------- fp16 gather-aggregate: one wave per node, lane = 2 channels.
// 8-deep then 4-deep manual unroll -> up to 8 feature loads in flight per wave.
__global__ __launch_bounds__(256) void aggregate_f16(
    const __half* __restrict__ feat16, const int* __restrict__ rowptr,
    const int* __restrict__ eidx, const float* __restrict__ invdeg,
    float* __restrict__ mean) {
    const int node = blockIdx.x * 4 + (threadIdx.x >> 6);
    if (node >= N_NODES) return;
    const int lane = threadIdx.x & 63;
    const int beg = rowptr[node];
    const int end = rowptr[node + 1];
    const size_t coff = (size_t)lane * 2;

    float2 a0 = {0.f, 0.f}, a1 = {0.f, 0.f}, a2 = {0.f, 0.f}, a3 = {0.f, 0.f};
    int i = beg;
    for (; i + 8 <= end; i += 8) {
        int s0 = eidx[i + 0], s1 = eidx[i + 1], s2 = eidx[i + 2], s3 = eidx[i + 3];
        int s4 = eidx[i + 4], s5 = eidx[i + 5], s6 = eidx[i + 6], s7 = eidx[i + 7];
        __half2 v0 = *(const __half2*)(feat16 + (size_t)s0 * 128 + coff);
        __half2 v1 = *(const __half2*)(feat16 + (size_t)s1 * 128 + coff);
        __half2 v2 = *(const __half2*)(feat16 + (size_t)s2 * 128 + coff);
        __half2 v3 = *(const __half2*)(feat16 + (size_t)s3 * 128 + coff);
        __half2 v4 = *(const __half2*)(feat16 + (size_t)s4 * 128 + coff);
        __half2 v5 = *(const __half2*)(feat16 + (size_t)s5 * 128 + coff);
        __half2 v6 = *(const __half2*)(feat16 + (size_t)s6 * 128 + coff);
        __half2 v7 = *(const __half2*)(feat16 + (size_t)s7 * 128 + coff);
        float2 f0 = __half22float2(v0), f1 = __half22float2(v1);
        float2 f2 = __half22float2(v2), f3 = __half22float2(v3);
        float2 f4 = __half22float2(v4), f5 = __half22float2(v5);
        float2 f6 = __half22float2(v6), f7 = __half22float2(v7);
        a0.x += f0.x; a0.y += f0.y;  a1.x += f1.x; a1.y += f1.y;
        a2.x += f2.x; a2.y += f2.y;  a3.x += f3.x; a3.y += f3.y;
        a0.x += f4.x; a0.y += f4.y;  a1.x += f5.x; a1.y += f5.y;
        a2.x += f6.x; a2.y += f6.y;  a3.x += f7.x; a3.y += f7.y;
    }
    if (i + 4 <= end) {
        int s0 = eidx[i + 0], s1 = eidx[i + 1], s2 = eidx[i + 2], s3 = eidx[i + 3];
        __half2 v0 = *(const __half2*)(feat16 + (size_t)s0 * 128 + coff);
        __half2 v1 = *(const __half2*)(feat16 + (size_t)s1 * 128 + coff);
        __half2 v2 = *(const __half2*)(feat16 + (size_t)s2 * 128 + coff);
        __half2 v3 = *(const __half2*)(feat16 + (size_t)s3 * 128 + coff);
        float2 f0 = __half22float2(v0), f1 = __half22float2(v1);
        float2 f2 = __half22float2(v2), f3 = __half22float2(v3);
        a0.x += f0.x; a0.y += f0.y;  a1.x += f1.x; a1.y += f1.y;
        a2.x += f2.x; a2.y += f2.y;  a3.x += f3.x; a3.y += f3.y;
        i += 4;
    }
    if (i + 2 <= end) {
        int s0 = eidx[i + 0], s1 = eidx[i + 1];
        __half2 v0 = *(const __half2*)(feat16 + (size_t)s0 * 128 + coff);
        __half2 v1 = *(const __half2*)(feat16 + (size_t)s1 * 128 + coff);
        float2 f0 = __half22float2(v0), f1 = __half22float2(v1);
        a0.x += f0.x; a0.y += f0.y;  a1.x += f1.x; a1.y += f1.y;
        i += 2;
    }
    if (i < end) {
        int s0 = eidx[i];
        float2 f0 = __half22float2(*(const __half2*)(feat16 + (size_t)s0 * 128 + coff));
        a0.x += f0.x; a0.y += f0.y;
    }

    const float sc = invdeg[node];
    float2 acc;
    acc.x = ((a0.x + a1.x) + (a2.x + a3.x)) * sc;
    acc.y = ((a0.y + a1.y) + (a2.y + a3.y)) * sc;
    *(float2*)(mean + (size_t)node * 128 + lane * 2) = acc;
}

// ---------------- split-bf16 MFMA SAGE GEMM (M=50000, N=128, K=256)
// C = Ah@Bh + Ah@Bl + Al@Bh  (lo*lo dropped, ~2^-16 relative)
#define GBM 64
#define GBK 32
#define ASTR 48   // ushorts per LDS row (32 data + 16 pad; 96 B, 16B-aligned)
#define BSTR 48

__global__ __launch_bounds__(256) void sage_gemm_mfma(
    const float* __restrict__ mean, const float* __restrict__ feat,
    const unsigned short* __restrict__ Whn, const unsigned short* __restrict__ Wln,
    const float* __restrict__ bias, float* __restrict__ out,
    __half* __restrict__ out16, int M) {
    __shared__ __align__(16) unsigned short Ah[GBM][ASTR];
    __shared__ __align__(16) unsigned short Al[GBM][ASTR];
    __shared__ __align__(16) unsigned short Bh[128][BSTR];
    __shared__ __align__(16) unsigned short Bl[128][BSTR];

    const int tid = threadIdx.x;
    const int wave = tid >> 6;
    const int lane = tid & 63;
    const int l15 = lane & 15;
    const int quad = lane >> 4;
    const int row0 = blockIdx.x * GBM;

    f32x4 acc[8];
#pragma unroll
    for (int t = 0; t < 8; ++t) acc[t] = (f32x4){0.f, 0.f, 0.f, 0.f};

    const int ar = tid >> 2;          // A stage: row 0..63
    const int ac = (tid & 3) * 8;     // A stage: k offset {0,8,16,24}

    for (int k0 = 0; k0 < 256; k0 += GBK) {
        // ---- stage A: fp32 -> bf16 hi/lo planes
        {
            int gi = row0 + ar;
            float va[8];
            if (gi < M) {
                const float* p = (k0 < 128) ? (mean + (size_t)gi * 128 + k0 + ac)
                                            : (feat + (size_t)gi * 128 + (k0 - 128) + ac);
                float4 v0 = *(const float4*)p;
                float4 v1 = *(const float4*)(p + 4);
                va[0] = v0.x; va[1] = v0.y; va[2] = v0.z; va[3] = v0.w;
                va[4] = v1.x; va[5] = v1.y; va[6] = v1.z; va[7] = v1.w;
            } else {
#pragma unroll
                for (int i = 0; i < 8; ++i) va[i] = 0.f;
            }
            ushort8 h, l;
#pragma unroll
            for (int i = 0; i < 8; ++i) {
                unsigned int u = __float_as_uint(va[i]);
                float hf = __uint_as_float(u & 0xFFFF0000u);
                float lf = va[i] - hf;           // exact residual
                h[i] = (unsigned short)(u >> 16);
                l[i] = (unsigned short)(__float_as_uint(lf) >> 16);
            }
            *(ushort8*)&Ah[ar][ac] = h;
            *(ushort8*)&Al[ar][ac] = l;
        }
        // ---- stage B: copy pre-split ushort planes (16B chunks)
#pragma unroll
        for (int i = 0; i < 2; ++i) {
            int id = tid + i * 256;              // 0..511
            int n = id >> 2;
            int kc = (id & 3) * 8;
            *(ushort8*)&Bh[n][kc] = *(const ushort8*)(Whn + (size_t)n * 256 + k0 + kc);
            *(ushort8*)&Bl[n][kc] = *(const ushort8*)(Wln + (size_t)n * 256 + k0 + kc);
        }
        __syncthreads();

        const short8 a_h = *(const short8*)&Ah[wave * 16 + l15][quad * 8];
        const short8 a_l = *(const short8*)&Al[wave * 16 + l15][quad * 8];
#pragma unroll
        for (int t = 0; t < 8; ++t) {
            const short8 b_h = *(const short8*)&Bh[t * 16 + l15][quad * 8];
            const short8 b_l = *(const short8*)&Bl[t * 16 + l15][quad * 8];
            acc[t] = __builtin_amdgcn_mfma_f32_16x16x32_bf16(a_h, b_h, acc[t], 0, 0, 0);
            acc[t] = __builtin_amdgcn_mfma_f32_16x16x32_bf16(a_h, b_l, acc[t], 0, 0, 0);
            acc[t] = __builtin_amdgcn_mfma_f32_16x16x32_bf16(a_l, b_h, acc[t], 0, 0, 0);
        }
        __syncthreads();
    }

    // epilogue: row = row0 + wave*16 + quad*4 + r, col = t*16 + l15
#pragma unroll
    for (int r = 0; r < 4; ++r) {
        int gi = row0 + wave * 16 + quad * 4 + r;
        if (gi < M) {
#pragma unroll
            for (int t = 0; t < 8; ++t) {
                int col = t * 16 + l15;
                float v = fmaxf(acc[t][r] + bias[col], 0.f);
                out[(size_t)gi * 128 + col] = v;
                if (out16) out16[(size_t)gi * 128 + col] = __float2half(v);
            }
        }
    }
}

// ---------------- pooling: batch is sorted; run-length accumulate, flush on change
#define POOL_CHUNK 128
__global__ void pool_kernel(const float* __restrict__ h, const int* __restrict__ batch,
                            float* __restrict__ pooled, float* __restrict__ cntf, int N) {
    int c = threadIdx.x;               // 0..127
    int n0 = blockIdx.x * POOL_CHUNK;
    int n1 = min(n0 + POOL_CHUNK, N);
    if (n0 >= N) return;
    float run = 0.0f;
    float runc = 0.0f;
    int curg = batch[n0];
    for (int n = n0; n < n1; ++n) {
        int g = batch[n];
        if (g != curg) {
            atomicAdd(&pooled[curg * 128 + c], run);
            if (c == 0) atomicAdd(&cntf[curg], runc);
            run = 0.0f; runc = 0.0f; curg = g;
        }
        run += h[(size_t)n * 128 + c];
        runc += 1.0f;
    }
    atomicAdd(&pooled[curg * 128 + c], run);
    if (c == 0) atomicAdd(&cntf[curg], runc);
}

// ---------------- final linear
__global__ void final_kernel(const float* __restrict__ pooled, const float* __restrict__ cntf,
                             const float* __restrict__ Wlin, const float* __restrict__ blin,
                             float* __restrict__ out) {
    int g = blockIdx.x;
    int j = threadIdx.x;               // 0..31
    float inv = 1.0f / fmaxf(cntf[g], 1.0f);
    float sum = blin[j];
    const float* prow = pooled + g * 128;
    const float* wrow = Wlin + j * 128;
    for (int c = 0; c < 128; ++c) sum += prow[c] * inv * wrow[c];
    out[g * 32 + j] = sum;
}

extern "C" void kernel_launch(void* const* d_in, const int* in_sizes, int n_in,
                              void* d_out, int out_size, void* d_ws, size_t ws_size,
                              hipStream_t stream) {
    const float* x    = (const float*)d_in[0];
    const int*   src  = (const int*)d_in[1];
    const int*   dst  = ((const int*)d_in[1]) + N_EDGES;
    const int*   batch= (const int*)d_in[2];
    const float* W1l  = (const float*)d_in[3];
    const float* b1   = (const float*)d_in[4];
    const float* W1r  = (const float*)d_in[5];
    const float* W2l  = (const float*)d_in[6];
    const float* b2   = (const float*)d_in[7];
    const float* W2r  = (const float*)d_in[8];
    const float* Wlin = (const float*)d_in[9];
    const float* blin = (const float*)d_in[10];
    float* out = (float*)d_out;

    float* ws      = (float*)d_ws;
    float* mean    = ws;                       // 6,400,000 f
    float* h1      = mean + 6400000;           // 6,400,000 f
    float* h2      = h1 + 6400000;             // 6,400,000 f
    __half* xh     = (__half*)(h2 + 6400000);  // 6,400,000 h (fp16 gather table; reused as h1h)
    float* pooled  = (float*)(xh + 6400000);   // 8,192 f
    float* cntf    = pooled + N_GRAPHS * 128;  // 64 f
    float* invdeg  = cntf + 64;                // 50,000 f
    unsigned short* Whn1 = (unsigned short*)(invdeg + N_NODES);  // 32,768 us
    unsigned short* Wln1 = Whn1 + 32768;
    unsigned short* Whn2 = Wln1 + 32768;
    unsigned short* Wln2 = Whn2 + 32768;
    int*   degi    = (int*)(Wln2 + 32768);     // 50,000 i   (adjacent to cursor: one memset)
    int*   cursor  = degi + N_NODES;           // 50,000 i
    int*   rowptr  = cursor + N_NODES;         // 50,001 i
    int*   eidx    = rowptr + N_NODES + 1;     // 600,000 i
    int*   bsum    = eidx + N_EDGES;           // 196 i
    int*   boff    = bsum + N_SCAN_BLOCKS;     // 196 i

    // zero accumulated-into scratch (ws is re-poisoned before every call)
    hipMemsetAsync(degi, 0, (size_t)(2 * N_NODES) * sizeof(int), stream);  // degi+cursor
    hipMemsetAsync(pooled, 0, (size_t)(N_GRAPHS * 128 + N_GRAPHS) * sizeof(float), stream);

    // weight prep + fp16 cast of x (independent of CSR build)
    build_w_bf16<<<128, 256, 0, stream>>>(W1l, W1r, Whn1, Wln1);
    build_w_bf16<<<128, 256, 0, stream>>>(W2l, W2r, Whn2, Wln2);
    cast_f16<<<(N_NODES * 128 / 4 + 255) / 256, 256, 0, stream>>>(x, xh, N_NODES * 128);

    // CSR build: coalesced 3-phase scan
    deg_kernel<<<(N_EDGES + 255) / 256, 256, 0, stream>>>(dst, degi, N_EDGES);
    scan_blocksum<<<N_SCAN_BLOCKS, SCAN_BLK, 0, stream>>>(degi, bsum);
    scan_boff<<<1, 256, 0, stream>>>(bsum, boff, rowptr);
    scan_emit<<<N_SCAN_BLOCKS, SCAN_BLK, 0, stream>>>(degi, boff, rowptr, invdeg);
    fill_kernel<<<(N_EDGES + 255) / 256, 256, 0, stream>>>(src, dst, rowptr, cursor, eidx, N_EDGES);

    const int gemm_grid = (N_NODES + GBM - 1) / GBM;   // 782

    // layer 1: fp16 gather + GEMM (epilogue also emits fp16 h1 into xh for layer 2)
    aggregate_f16<<<(N_NODES + 3) / 4, 256, 0, stream>>>(xh, rowptr, eidx, invdeg, mean);
    sage_gemm_mfma<<<gemm_grid, 256, 0, stream>>>(mean, x, Whn1, Wln1, b1, h1, xh, N_NODES);

    // layer 2
    aggregate_f16<<<(N_NODES + 3) / 4, 256, 0, stream>>>(xh, rowptr, eidx, invdeg, mean);
    sage_gemm_mfma<<<gemm_grid, 256, 0, stream>>>(mean, h1, Whn2, Wln2, b2, h2,
                                                  (__half*)nullptr, N_NODES);

    // pool + final linear
    pool_kernel<<<(N_NODES + POOL_CHUNK - 1) / POOL_CHUNK, 128, 0, stream>>>(h2, batch, pooled, cntf, N_NODES);
    final_kernel<<<N_GRAPHS, 32, 0, stream>>>(pooled, cntf, Wlin, blin, out);
}

// Round 7
// 283.416 us; speedup vs baseline: 1.2254x; 1.0779x over previous
//
#include <hip/hip_runtime.h>
#include <hip/hip_fp16.h>

#define N_NODES 50000
#define N_EDGES 600000
#define N_GRAPHS 64
#define HID 128
#define OUT_C 32

#define SCAN_BLK 256
#define N_SCAN_BLOCKS ((N_NODES + SCAN_BLK - 1) / SCAN_BLK)   // 196

typedef __attribute__((ext_vector_type(8))) short short8;
typedef __attribute__((ext_vector_type(8))) unsigned short ushort8;
typedef __attribute__((ext_vector_type(4))) float f32x4;

// ---------------- weight prep: split-bf16 planes, n-major (B^T layout, contiguous k)
__global__ void build_w_bf16(const float* __restrict__ Wl, const float* __restrict__ Wr,
                             unsigned short* __restrict__ Whn, unsigned short* __restrict__ Wln) {
    int idx = blockIdx.x * 256 + threadIdx.x;   // 0..32767
    int n = idx >> 8, k = idx & 255;
    float a = (k < 128) ? Wl[n * 128 + k] : Wr[n * 128 + (k - 128)];
    unsigned int u = __float_as_uint(a);
    float hf = __uint_as_float(u & 0xFFFF0000u);
    float lf = a - hf;                 // exact (low mantissa bits)
    Whn[idx] = (unsigned short)(u >> 16);
    Wln[idx] = (unsigned short)(__float_as_uint(lf) >> 16);
}

// ---------------- fp32 -> fp16 cast (vectorized)
__global__ void cast_f16(const float* __restrict__ in, __half* __restrict__ out, int n) {
    int i = (blockIdx.x * 256 + threadIdx.x) * 4;
    if (i < n) {
        float4 v = *(const float4*)(in + i);
        __half2 a = __floats2half2_rn(v.x, v.y);
        __half2 b = __floats2half2_rn(v.z, v.w);
        uint2 st;
        st.x = *(const unsigned int*)&a;
        st.y = *(const unsigned int*)&b;
        *(uint2*)(out + i) = st;
    }
}

// ---------------- CSR build
__global__ void deg_kernel(const int* __restrict__ dst, int* __restrict__ deg, int E) {
    int e = blockIdx.x * 256 + threadIdx.x;
    if (e < E) atomicAdd(&deg[dst[e]], 1);
}

__global__ __launch_bounds__(SCAN_BLK) void scan_blocksum(
    const int* __restrict__ deg, int* __restrict__ bsum) {
    __shared__ int s[SCAN_BLK];
    int i = blockIdx.x * SCAN_BLK + threadIdx.x;
    s[threadIdx.x] = (i < N_NODES) ? deg[i] : 0;
    __syncthreads();
    for (int off = SCAN_BLK / 2; off > 0; off >>= 1) {
        if (threadIdx.x < off) s[threadIdx.x] += s[threadIdx.x + off];
        __syncthreads();
    }
    if (threadIdx.x == 0) bsum[blockIdx.x] = s[0];
}

__global__ __launch_bounds__(256) void scan_boff(
    const int* __restrict__ bsum, int* __restrict__ boff, int* __restrict__ rowptr) {
    __shared__ int s[256];
    int t = threadIdx.x;
    int v = (t < N_SCAN_BLOCKS) ? bsum[t] : 0;
    s[t] = v;
    __syncthreads();
    for (int off = 1; off < 256; off <<= 1) {
        int u = (t >= off) ? s[t - off] : 0;
        __syncthreads();
        s[t] += u;
        __syncthreads();
    }
    if (t < N_SCAN_BLOCKS) boff[t] = s[t] - v;
    if (t == N_SCAN_BLOCKS - 1) rowptr[N_NODES] = s[t];
}

__global__ __launch_bounds__(SCAN_BLK) void scan_emit(
    const int* __restrict__ deg, const int* __restrict__ boff,
    int* __restrict__ rowptr, float* __restrict__ invdeg) {
    __shared__ int s[SCAN_BLK];
    int i = blockIdx.x * SCAN_BLK + threadIdx.x;
    int t = threadIdx.x;
    int v = (i < N_NODES) ? deg[i] : 0;
    s[t] = v;
    __syncthreads();
    for (int off = 1; off < SCAN_BLK; off <<= 1) {
        int u = (t >= off) ? s[t - off] : 0;
        __syncthreads();
        s[t] += u;
        __syncthreads();
    }
    if (i < N_NODES) {
        rowptr[i] = boff[blockIdx.x] + s[t] - v;
        invdeg[i] = 1.0f / fmaxf((float)v, 1.0f);
    }
}

__global__ void fill_kernel(const int* __restrict__ src, const int* __restrict__ dst,
                            const int* __restrict__ rowptr, int* __restrict__ cursor,
                            int* __restrict__ eidx, int E) {
    int e = blockIdx.x * 256 + threadIdx.x;
    if (e < E) {
        int d = dst[e];
        int pos = atomicAdd(&cursor[d], 1);
        eidx[rowptr[d] + pos] = src[e];
    }
}

// ---------------- fp16 gather-aggregate: one wave per node, lane = 2 channels.
// 8-deep then 4-deep manual unroll -> up to 8 feature loads in flight per wave.
__global__ __launch_bounds__(256) void aggregate_f16(
    const __half* __restrict__ feat16, const int* __restrict__ rowptr,
    const int* __restrict__ eidx, const float* __restrict__ invdeg,
    float* __restrict__ mean) {
    const int node = blockIdx.x * 4 + (threadIdx.x >> 6);
    if (node >= N_NODES) return;
    const int lane = threadIdx.x & 63;
    const int beg = rowptr[node];
    const int end = rowptr[node + 1];
    const size_t coff = (size_t)lane * 2;

    float2 a0 = {0.f, 0.f}, a1 = {0.f, 0.f}, a2 = {0.f, 0.f}, a3 = {0.f, 0.f};
    int i = beg;
    for (; i + 8 <= end; i += 8) {
        int s0 = eidx[i + 0], s1 = eidx[i + 1], s2 = eidx[i + 2], s3 = eidx[i + 3];
        int s4 = eidx[i + 4], s5 = eidx[i + 5], s6 = eidx[i + 6], s7 = eidx[i + 7];
        __half2 v0 = *(const __half2*)(feat16 + (size_t)s0 * 128 + coff);
        __half2 v1 = *(const __half2*)(feat16 + (size_t)s1 * 128 + coff);
        __half2 v2 = *(const __half2*)(feat16 + (size_t)s2 * 128 + coff);
        __half2 v3 = *(const __half2*)(feat16 + (size_t)s3 * 128 + coff);
        __half2 v4 = *(const __half2*)(feat16 + (size_t)s4 * 128 + coff);
        __half2 v5 = *(const __half2*)(feat16 + (size_t)s5 * 128 + coff);
        __half2 v6 = *(const __half2*)(feat16 + (size_t)s6 * 128 + coff);
        __half2 v7 = *(const __half2*)(feat16 + (size_t)s7 * 128 + coff);
        float2 f0 = __half22float2(v0), f1 = __half22float2(v1);
        float2 f2 = __half22float2(v2), f3 = __half22float2(v3);
        float2 f4 = __half22float2(v4), f5 = __half22float2(v5);
        float2 f6 = __half22float2(v6), f7 = __half22float2(v7);
        a0.x += f0.x; a0.y += f0.y;  a1.x += f1.x; a1.y += f1.y;
        a2.x += f2.x; a2.y += f2.y;  a3.x += f3.x; a3.y += f3.y;
        a0.x += f4.x; a0.y += f4.y;  a1.x += f5.x; a1.y += f5.y;
        a2.x += f6.x; a2.y += f6.y;  a3.x += f7.x; a3.y += f7.y;
    }
    if (i + 4 <= end) {
        int s0 = eidx[i + 0], s1 = eidx[i + 1], s2 = eidx[i + 2], s3 = eidx[i + 3];
        __half2 v0 = *(const __half2*)(feat16 + (size_t)s0 * 128 + coff);
        __half2 v1 = *(const __half2*)(feat16 + (size_t)s1 * 128 + coff);
        __half2 v2 = *(const __half2*)(feat16 + (size_t)s2 * 128 + coff);
        __half2 v3 = *(const __half2*)(feat16 + (size_t)s3 * 128 + coff);
        float2 f0 = __half22float2(v0), f1 = __half22float2(v1);
        float2 f2 = __half22float2(v2), f3 = __half22float2(v3);
        a0.x += f0.x; a0.y += f0.y;  a1.x += f1.x; a1.y += f1.y;
        a2.x += f2.x; a2.y += f2.y;  a3.x += f3.x; a3.y += f3.y;
        i += 4;
    }
    if (i + 2 <= end) {
        int s0 = eidx[i + 0], s1 = eidx[i + 1];
        __half2 v0 = *(const __half2*)(feat16 + (size_t)s0 * 128 + coff);
        __half2 v1 = *(const __half2*)(feat16 + (size_t)s1 * 128 + coff);
        float2 f0 = __half22float2(v0), f1 = __half22float2(v1);
        a0.x += f0.x; a0.y += f0.y;  a1.x += f1.x; a1.y += f1.y;
        i += 2;
    }
    if (i < end) {
        int s0 = eidx[i];
        float2 f0 = __half22float2(*(const __half2*)(feat16 + (size_t)s0 * 128 + coff));
        a0.x += f0.x; a0.y += f0.y;
    }

    const float sc = invdeg[node];
    float2 acc;
    acc.x = ((a0.x + a1.x) + (a2.x + a3.x)) * sc;
    acc.y = ((a0.y + a1.y) + (a2.y + a3.y)) * sc;
    *(float2*)(mean + (size_t)node * 128 + lane * 2) = acc;
}

// ---------------- split-bf16 MFMA SAGE GEMM (M=50000, N=128, K=256)
// C = Ah@Bh + Ah@Bl + Al@Bh  (lo*lo dropped, ~2^-16 relative)
#define GBM 64
#define GBK 32
#define ASTR 48   // ushorts per LDS row (32 data + 16 pad; 96 B, 16B-aligned)
#define BSTR 48

__global__ __launch_bounds__(256) void sage_gemm_mfma(
    const float* __restrict__ mean, const float* __restrict__ feat,
    const unsigned short* __restrict__ Whn, const unsigned short* __restrict__ Wln,
    const float* __restrict__ bias, float* __restrict__ out,
    __half* __restrict__ out16, int M) {
    __shared__ __align__(16) unsigned short Ah[GBM][ASTR];
    __shared__ __align__(16) unsigned short Al[GBM][ASTR];
    __shared__ __align__(16) unsigned short Bh[128][BSTR];
    __shared__ __align__(16) unsigned short Bl[128][BSTR];

    const int tid = threadIdx.x;
    const int wave = tid >> 6;
    const int lane = tid & 63;
    const int l15 = lane & 15;
    const int quad = lane >> 4;
    const int row0 = blockIdx.x * GBM;

    f32x4 acc[8];
#pragma unroll
    for (int t = 0; t < 8; ++t) acc[t] = (f32x4){0.f, 0.f, 0.f, 0.f};

    const int ar = tid >> 2;          // A stage: row 0..63
    const int ac = (tid & 3) * 8;     // A stage: k offset {0,8,16,24}

    for (int k0 = 0; k0 < 256; k0 += GBK) {
        // ---- stage A: fp32 -> bf16 hi/lo planes
        {
            int gi = row0 + ar;
            float va[8];
            if (gi < M) {
                const float* p = (k0 < 128) ? (mean + (size_t)gi * 128 + k0 + ac)
                                            : (feat + (size_t)gi * 128 + (k0 - 128) + ac);
                float4 v0 = *(const float4*)p;
                float4 v1 = *(const float4*)(p + 4);
                va[0] = v0.x; va[1] = v0.y; va[2] = v0.z; va[3] = v0.w;
                va[4] = v1.x; va[5] = v1.y; va[6] = v1.z; va[7] = v1.w;
            } else {
#pragma unroll
                for (int i = 0; i < 8; ++i) va[i] = 0.f;
            }
            ushort8 h, l;
#pragma unroll
            for (int i = 0; i < 8; ++i) {
                unsigned int u = __float_as_uint(va[i]);
                float hf = __uint_as_float(u & 0xFFFF0000u);
                float lf = va[i] - hf;           // exact residual
                h[i] = (unsigned short)(u >> 16);
                l[i] = (unsigned short)(__float_as_uint(lf) >> 16);
            }
            *(ushort8*)&Ah[ar][ac] = h;
            *(ushort8*)&Al[ar][ac] = l;
        }
        // ---- stage B: copy pre-split ushort planes (16B chunks)
#pragma unroll
        for (int i = 0; i < 2; ++i) {
            int id = tid + i * 256;              // 0..511
            int n = id >> 2;
            int kc = (id & 3) * 8;
            *(ushort8*)&Bh[n][kc] = *(const ushort8*)(Whn + (size_t)n * 256 + k0 + kc);
            *(ushort8*)&Bl[n][kc] = *(const ushort8*)(Wln + (size_t)n * 256 + k0 + kc);
        }
        __syncthreads();

        const short8 a_h = *(const short8*)&Ah[wave * 16 + l15][quad * 8];
        const short8 a_l = *(const short8*)&Al[wave * 16 + l15][quad * 8];
#pragma unroll
        for (int t = 0; t < 8; ++t) {
            const short8 b_h = *(const short8*)&Bh[t * 16 + l15][quad * 8];
            const short8 b_l = *(const short8*)&Bl[t * 16 + l15][quad * 8];
            acc[t] = __builtin_amdgcn_mfma_f32_16x16x32_bf16(a_h, b_h, acc[t], 0, 0, 0);
            acc[t] = __builtin_amdgcn_mfma_f32_16x16x32_bf16(a_h, b_l, acc[t], 0, 0, 0);
            acc[t] = __builtin_amdgcn_mfma_f32_16x16x32_bf16(a_l, b_h, acc[t], 0, 0, 0);
        }
        __syncthreads();
    }

    // epilogue: row = row0 + wave*16 + quad*4 + r, col = t*16 + l15
#pragma unroll
    for (int r = 0; r < 4; ++r) {
        int gi = row0 + wave * 16 + quad * 4 + r;
        if (gi < M) {
#pragma unroll
            for (int t = 0; t < 8; ++t) {
                int col = t * 16 + l15;
                float v = fmaxf(acc[t][r] + bias[col], 0.f);
                out[(size_t)gi * 128 + col] = v;
                if (out16) out16[(size_t)gi * 128 + col] = __float2half(v);
            }
        }
    }
}

// ---------------- pooling: 4 blocks per graph, coalesced float4 strided reads,
// LDS reduce, one atomicAdd per channel per block. batch is sorted.
#define POOL_PARTS 4
__global__ __launch_bounds__(256) void pool_graph(
    const float* __restrict__ h, const int* __restrict__ batch,
    float* __restrict__ pooled, int* __restrict__ gcnt) {
    const int g = blockIdx.x >> 2;
    const int part = blockIdx.x & 3;
    // lower_bound(batch, g) and lower_bound(batch, g+1)
    int lo = 0, hi = N_NODES;
    while (lo < hi) { int mid = (lo + hi) >> 1; if (batch[mid] < g) lo = mid + 1; else hi = mid; }
    const int start = lo;
    hi = N_NODES;
    while (lo < hi) { int mid = (lo + hi) >> 1; if (batch[mid] < g + 1) lo = mid + 1; else hi = mid; }
    const int end = lo;

    const int t = threadIdx.x;
    if (part == 0 && t == 0) gcnt[g] = end - start;

    const int c4 = (t & 31) * 4;       // channel group (float4)
    const int rg = t >> 5;             // 0..7 row group
    float4 acc = {0.f, 0.f, 0.f, 0.f};
    for (int n = start + part * 8 + rg; n < end; n += 8 * POOL_PARTS) {
        float4 v = *(const float4*)(h + (size_t)n * 128 + c4);
        acc.x += v.x; acc.y += v.y; acc.z += v.z; acc.w += v.w;
    }
    __shared__ float sm[8][132];
    sm[rg][c4 + 0] = acc.x;
    sm[rg][c4 + 1] = acc.y;
    sm[rg][c4 + 2] = acc.z;
    sm[rg][c4 + 3] = acc.w;
    __syncthreads();
    if (t < 128) {
        float s = 0.f;
#pragma unroll
        for (int r = 0; r < 8; ++r) s += sm[r][t];
        atomicAdd(&pooled[g * 128 + t], s);
    }
}

// ---------------- final linear: out[g][j] = blin[j] + sum_c (pooled[g][c]/cnt) * Wlin[j][c]
__global__ void final_kernel(const float* __restrict__ pooled, const int* __restrict__ gcnt,
                             const float* __restrict__ Wlin, const float* __restrict__ blin,
                             float* __restrict__ out) {
    int g = blockIdx.x;
    int j = threadIdx.x;               // 0..31
    float inv = 1.0f / fmaxf((float)gcnt[g], 1.0f);
    float sum = blin[j];
    const float* prow = pooled + g * 128;
    const float* wrow = Wlin + j * 128;
    for (int c = 0; c < 128; ++c) sum += prow[c] * inv * wrow[c];
    out[g * 32 + j] = sum;
}

extern "C" void kernel_launch(void* const* d_in, const int* in_sizes, int n_in,
                              void* d_out, int out_size, void* d_ws, size_t ws_size,
                              hipStream_t stream) {
    const float* x    = (const float*)d_in[0];
    const int*   src  = (const int*)d_in[1];
    const int*   dst  = ((const int*)d_in[1]) + N_EDGES;
    const int*   batch= (const int*)d_in[2];
    const float* W1l  = (const float*)d_in[3];
    const float* b1   = (const float*)d_in[4];
    const float* W1r  = (const float*)d_in[5];
    const float* W2l  = (const float*)d_in[6];
    const float* b2   = (const float*)d_in[7];
    const float* W2r  = (const float*)d_in[8];
    const float* Wlin = (const float*)d_in[9];
    const float* blin = (const float*)d_in[10];
    float* out = (float*)d_out;

    float* ws      = (float*)d_ws;
    float* mean    = ws;                       // 6,400,000 f
    float* h1      = mean + 6400000;           // 6,400,000 f
    float* h2      = h1 + 6400000;             // 6,400,000 f
    __half* xh     = (__half*)(h2 + 6400000);  // 6,400,000 h (fp16 gather table; reused as h1h)
    float* pooled  = (float*)(xh + 6400000);   // 8,192 f
    int*   gcnt    = (int*)(pooled + N_GRAPHS * 128); // 64 i
    float* invdeg  = (float*)(gcnt + 64);      // 50,000 f
    unsigned short* Whn1 = (unsigned short*)(invdeg + N_NODES);  // 32,768 us
    unsigned short* Wln1 = Whn1 + 32768;
    unsigned short* Whn2 = Wln1 + 32768;
    unsigned short* Wln2 = Whn2 + 32768;
    int*   degi    = (int*)(Wln2 + 32768);     // 50,000 i   (adjacent to cursor: one memset)
    int*   cursor  = degi + N_NODES;           // 50,000 i
    int*   rowptr  = cursor + N_NODES;         // 50,001 i
    int*   eidx    = rowptr + N_NODES + 1;     // 600,000 i
    int*   bsum    = eidx + N_EDGES;           // 196 i
    int*   boff    = bsum + N_SCAN_BLOCKS;     // 196 i

    // zero accumulated-into scratch (ws is re-poisoned before every call)
    hipMemsetAsync(degi, 0, (size_t)(2 * N_NODES) * sizeof(int), stream);  // degi+cursor
    hipMemsetAsync(pooled, 0, (size_t)(N_GRAPHS * 128) * sizeof(float), stream);

    // weight prep + fp16 cast of x (independent of CSR build)
    build_w_bf16<<<128, 256, 0, stream>>>(W1l, W1r, Whn1, Wln1);
    build_w_bf16<<<128, 256, 0, stream>>>(W2l, W2r, Whn2, Wln2);
    cast_f16<<<(N_NODES * 128 / 4 + 255) / 256, 256, 0, stream>>>(x, xh, N_NODES * 128);

    // CSR build: coalesced 3-phase scan
    deg_kernel<<<(N_EDGES + 255) / 256, 256, 0, stream>>>(dst, degi, N_EDGES);
    scan_blocksum<<<N_SCAN_BLOCKS, SCAN_BLK, 0, stream>>>(degi, bsum);
    scan_boff<<<1, 256, 0, stream>>>(bsum, boff, rowptr);
    scan_emit<<<N_SCAN_BLOCKS, SCAN_BLK, 0, stream>>>(degi, boff, rowptr, invdeg);
    fill_kernel<<<(N_EDGES + 255) / 256, 256, 0, stream>>>(src, dst, rowptr, cursor, eidx, N_EDGES);

    const int gemm_grid = (N_NODES + GBM - 1) / GBM;   // 782

    // layer 1: fp16 gather + GEMM (epilogue also emits fp16 h1 into xh for layer 2)
    aggregate_f16<<<(N_NODES + 3) / 4, 256, 0, stream>>>(xh, rowptr, eidx, invdeg, mean);
    sage_gemm_mfma<<<gemm_grid, 256, 0, stream>>>(mean, x, Whn1, Wln1, b1, h1, xh, N_NODES);

    // layer 2
    aggregate_f16<<<(N_NODES + 3) / 4, 256, 0, stream>>>(xh, rowptr, eidx, invdeg, mean);
    sage_gemm_mfma<<<gemm_grid, 256, 0, stream>>>(mean, h1, Whn2, Wln2, b2, h2,
                                                  (__half*)nullptr, N_NODES);

    // pool + final linear
    pool_graph<<<N_GRAPHS * POOL_PARTS, 256, 0, stream>>>(h2, batch, pooled, gcnt);
    final_kernel<<<N_GRAPHS, 32, 0, stream>>>(pooled, gcnt, Wlin, blin, out);
}

// Round 8
// 272.346 us; speedup vs baseline: 1.2752x; 1.0406x over previous
//
#include <hip/hip_runtime.h>
#include <hip/hip_fp16.h>

#define N_NODES 50000
#define N_EDGES 600000
#define N_GRAPHS 64
#define HID 128
#define OUT_C 32

#define SCAN_BLK 256
#define N_SCAN_BLOCKS ((N_NODES + SCAN_BLK - 1) / SCAN_BLK)   // 196

typedef __attribute__((ext_vector_type(8))) _Float16 half8;
typedef __attribute__((ext_vector_type(4))) float f32x4;

// ---------------- weight prep: split-fp16 planes, n-major (B^T layout, contiguous k)
// Wh[n][k] = fp16( k<128 ? Wl_w[n][k] : Wr_w[n][k-128] ), Wl = fp16 of residual
__global__ void build_w_f16(const float* __restrict__ Wlw, const float* __restrict__ Wrw,
                            __half* __restrict__ Wh, __half* __restrict__ Wl) {
    int idx = blockIdx.x * 256 + threadIdx.x;   // 0..32767
    int n = idx >> 8, k = idx & 255;
    float a = (k < 128) ? Wlw[n * 128 + k] : Wrw[n * 128 + (k - 128)];
    __half hh = __float2half(a);
    float hf = __half2float(hh);
    Wh[idx] = hh;
    Wl[idx] = __float2half(a - hf);
}

// ---------------- fp32 -> fp16 cast (vectorized)
__global__ void cast_f16(const float* __restrict__ in, __half* __restrict__ out, int n) {
    int i = (blockIdx.x * 256 + threadIdx.x) * 4;
    if (i < n) {
        float4 v = *(const float4*)(in + i);
        __half2 a = __floats2half2_rn(v.x, v.y);
        __half2 b = __floats2half2_rn(v.z, v.w);
        uint2 st;
        st.x = *(const unsigned int*)&a;
        st.y = *(const unsigned int*)&b;
        *(uint2*)(out + i) = st;
    }
}

// ---------------- CSR build
__global__ void deg_kernel(const int* __restrict__ dst, int* __restrict__ deg, int E) {
    int e = blockIdx.x * 256 + threadIdx.x;
    if (e < E) atomicAdd(&deg[dst[e]], 1);
}

__global__ __launch_bounds__(SCAN_BLK) void scan_blocksum(
    const int* __restrict__ deg, int* __restrict__ bsum) {
    __shared__ int s[SCAN_BLK];
    int i = blockIdx.x * SCAN_BLK + threadIdx.x;
    s[threadIdx.x] = (i < N_NODES) ? deg[i] : 0;
    __syncthreads();
    for (int off = SCAN_BLK / 2; off > 0; off >>= 1) {
        if (threadIdx.x < off) s[threadIdx.x] += s[threadIdx.x + off];
        __syncthreads();
    }
    if (threadIdx.x == 0) bsum[blockIdx.x] = s[0];
}

__global__ __launch_bounds__(256) void scan_boff(
    const int* __restrict__ bsum, int* __restrict__ boff, int* __restrict__ rowptr) {
    __shared__ int s[256];
    int t = threadIdx.x;
    int v = (t < N_SCAN_BLOCKS) ? bsum[t] : 0;
    s[t] = v;
    __syncthreads();
    for (int off = 1; off < 256; off <<= 1) {
        int u = (t >= off) ? s[t - off] : 0;
        __syncthreads();
        s[t] += u;
        __syncthreads();
    }
    if (t < N_SCAN_BLOCKS) boff[t] = s[t] - v;
    if (t == N_SCAN_BLOCKS - 1) rowptr[N_NODES] = s[t];
}

__global__ __launch_bounds__(SCAN_BLK) void scan_emit(
    const int* __restrict__ deg, const int* __restrict__ boff,
    int* __restrict__ rowptr, float* __restrict__ invdeg) {
    __shared__ int s[SCAN_BLK];
    int i = blockIdx.x * SCAN_BLK + threadIdx.x;
    int t = threadIdx.x;
    int v = (i < N_NODES) ? deg[i] : 0;
    s[t] = v;
    __syncthreads();
    for (int off = 1; off < SCAN_BLK; off <<= 1) {
        int u = (t >= off) ? s[t - off] : 0;
        __syncthreads();
        s[t] += u;
        __syncthreads();
    }
    if (i < N_NODES) {
        rowptr[i] = boff[blockIdx.x] + s[t] - v;
        invdeg[i] = 1.0f / fmaxf((float)v, 1.0f);
    }
}

__global__ void fill_kernel(const int* __restrict__ src, const int* __restrict__ dst,
                            const int* __restrict__ rowptr, int* __restrict__ cursor,
                            int* __restrict__ eidx, int E) {
    int e = blockIdx.x * 256 + threadIdx.x;
    if (e < E) {
        int d = dst[e];
        int pos = atomicAdd(&cursor[d], 1);
        eidx[rowptr[d] + pos] = src[e];
    }
}

// ---------------- fp16 gather-aggregate: one wave per node, lane = 2 channels.
// 8/4/2-deep manual unroll -> up to 8 feature loads in flight per wave. fp16 mean out.
__global__ __launch_bounds__(256) void aggregate_f16(
    const __half* __restrict__ feat16, const int* __restrict__ rowptr,
    const int* __restrict__ eidx, const float* __restrict__ invdeg,
    __half* __restrict__ mean16) {
    const int node = blockIdx.x * 4 + (threadIdx.x >> 6);
    if (node >= N_NODES) return;
    const int lane = threadIdx.x & 63;
    const int beg = rowptr[node];
    const int end = rowptr[node + 1];
    const size_t coff = (size_t)lane * 2;

    float2 a0 = {0.f, 0.f}, a1 = {0.f, 0.f}, a2 = {0.f, 0.f}, a3 = {0.f, 0.f};
    int i = beg;
    for (; i + 8 <= end; i += 8) {
        int s0 = eidx[i + 0], s1 = eidx[i + 1], s2 = eidx[i + 2], s3 = eidx[i + 3];
        int s4 = eidx[i + 4], s5 = eidx[i + 5], s6 = eidx[i + 6], s7 = eidx[i + 7];
        __half2 v0 = *(const __half2*)(feat16 + (size_t)s0 * 128 + coff);
        __half2 v1 = *(const __half2*)(feat16 + (size_t)s1 * 128 + coff);
        __half2 v2 = *(const __half2*)(feat16 + (size_t)s2 * 128 + coff);
        __half2 v3 = *(const __half2*)(feat16 + (size_t)s3 * 128 + coff);
        __half2 v4 = *(const __half2*)(feat16 + (size_t)s4 * 128 + coff);
        __half2 v5 = *(const __half2*)(feat16 + (size_t)s5 * 128 + coff);
        __half2 v6 = *(const __half2*)(feat16 + (size_t)s6 * 128 + coff);
        __half2 v7 = *(const __half2*)(feat16 + (size_t)s7 * 128 + coff);
        float2 f0 = __half22float2(v0), f1 = __half22float2(v1);
        float2 f2 = __half22float2(v2), f3 = __half22float2(v3);
        float2 f4 = __half22float2(v4), f5 = __half22float2(v5);
        float2 f6 = __half22float2(v6), f7 = __half22float2(v7);
        a0.x += f0.x; a0.y += f0.y;  a1.x += f1.x; a1.y += f1.y;
        a2.x += f2.x; a2.y += f2.y;  a3.x += f3.x; a3.y += f3.y;
        a0.x += f4.x; a0.y += f4.y;  a1.x += f5.x; a1.y += f5.y;
        a2.x += f6.x; a2.y += f6.y;  a3.x += f7.x; a3.y += f7.y;
    }
    if (i + 4 <= end) {
        int s0 = eidx[i + 0], s1 = eidx[i + 1], s2 = eidx[i + 2], s3 = eidx[i + 3];
        __half2 v0 = *(const __half2*)(feat16 + (size_t)s0 * 128 + coff);
        __half2 v1 = *(const __half2*)(feat16 + (size_t)s1 * 128 + coff);
        __half2 v2 = *(const __half2*)(feat16 + (size_t)s2 * 128 + coff);
        __half2 v3 = *(const __half2*)(feat16 + (size_t)s3 * 128 + coff);
        float2 f0 = __half22float2(v0), f1 = __half22float2(v1);
        float2 f2 = __half22float2(v2), f3 = __half22float2(v3);
        a0.x += f0.x; a0.y += f0.y;  a1.x += f1.x; a1.y += f1.y;
        a2.x += f2.x; a2.y += f2.y;  a3.x += f3.x; a3.y += f3.y;
        i += 4;
    }
    if (i + 2 <= end) {
        int s0 = eidx[i + 0], s1 = eidx[i + 1];
        __half2 v0 = *(const __half2*)(feat16 + (size_t)s0 * 128 + coff);
        __half2 v1 = *(const __half2*)(feat16 + (size_t)s1 * 128 + coff);
        float2 f0 = __half22float2(v0), f1 = __half22float2(v1);
        a0.x += f0.x; a0.y += f0.y;  a1.x += f1.x; a1.y += f1.y;
        i += 2;
    }
    if (i < end) {
        int s0 = eidx[i];
        float2 f0 = __half22float2(*(const __half2*)(feat16 + (size_t)s0 * 128 + coff));
        a0.x += f0.x; a0.y += f0.y;
    }

    const float sc = invdeg[node];
    float mx = ((a0.x + a1.x) + (a2.x + a3.x)) * sc;
    float my = ((a0.y + a1.y) + (a2.y + a3.y)) * sc;
    *(__half2*)(mean16 + (size_t)node * 128 + lane * 2) = __floats2half2_rn(mx, my);
}

// ---------------- split-fp16 MFMA SAGE GEMM (M=50000, N=128, K=256)
// C = A@(Bh+Bl), A fp16 (2^-11 rel), B split-fp16 (near-exact).
// A fragments pre-loaded to registers (no A LDS); B staged per-32k chunk.
#define GBM 64
#define BSTR 48   // halfs per LDS row (32 data + 16 pad; 96 B, 16B-aligned)

__global__ __launch_bounds__(256) void sage_gemm_f16(
    const __half* __restrict__ mean16, const __half* __restrict__ feat16,
    const __half* __restrict__ Wh, const __half* __restrict__ Wl,
    const float* __restrict__ bias, __half* __restrict__ out16, int M) {
    __shared__ __align__(16) __half Bh[128][BSTR];
    __shared__ __align__(16) __half Bl[128][BSTR];

    const int tid = threadIdx.x;
    const int wave = tid >> 6;
    const int lane = tid & 63;
    const int l15 = lane & 15;
    const int quad = lane >> 4;
    const int row0 = blockIdx.x * GBM;
    const int gi_a = min(row0 + wave * 16 + l15, M - 1);   // clamp OOB rows (stores guarded)

    // prefetch all 8 A fragments (16 B each, 64B-line coalesced across l15)
    half8 af[8];
#pragma unroll
    for (int kb = 0; kb < 8; ++kb) {
        const int k0 = kb * 32;
        const __half* ap = (k0 < 128)
            ? (mean16 + (size_t)gi_a * 128 + k0 + quad * 8)
            : (feat16 + (size_t)gi_a * 128 + (k0 - 128) + quad * 8);
        af[kb] = *(const half8*)ap;
    }

    f32x4 acc[8];
#pragma unroll
    for (int t = 0; t < 8; ++t) acc[t] = (f32x4){0.f, 0.f, 0.f, 0.f};

#pragma unroll
    for (int kb = 0; kb < 8; ++kb) {
        const int k0 = kb * 32;
        // stage B chunk: 128 n x 32 k, both planes, 16B copies
#pragma unroll
        for (int i = 0; i < 2; ++i) {
            int id = tid + i * 256;              // 0..511
            int n = id >> 2;
            int kc = (id & 3) * 8;
            *(half8*)&Bh[n][kc] = *(const half8*)(Wh + (size_t)n * 256 + k0 + kc);
            *(half8*)&Bl[n][kc] = *(const half8*)(Wl + (size_t)n * 256 + k0 + kc);
        }
        __syncthreads();

#pragma unroll
        for (int t = 0; t < 8; ++t) {
            const half8 b_h = *(const half8*)&Bh[t * 16 + l15][quad * 8];
            const half8 b_l = *(const half8*)&Bl[t * 16 + l15][quad * 8];
            acc[t] = __builtin_amdgcn_mfma_f32_16x16x32_f16(af[kb], b_h, acc[t], 0, 0, 0);
            acc[t] = __builtin_amdgcn_mfma_f32_16x16x32_f16(af[kb], b_l, acc[t], 0, 0, 0);
        }
        __syncthreads();
    }

    // epilogue: row = row0 + wave*16 + quad*4 + r, col = t*16 + l15
#pragma unroll
    for (int r = 0; r < 4; ++r) {
        int gi = row0 + wave * 16 + quad * 4 + r;
        if (gi < M) {
#pragma unroll
            for (int t = 0; t < 8; ++t) {
                int col = t * 16 + l15;
                float v = fmaxf(acc[t][r] + bias[col], 0.f);
                out16[(size_t)gi * 128 + col] = __float2half(v);
            }
        }
    }
}

// ---------------- pooling: 4 blocks per graph, coalesced strided fp16 reads,
// LDS reduce, one atomicAdd per channel per block. batch is sorted.
#define POOL_PARTS 4
__global__ __launch_bounds__(256) void pool_graph(
    const __half* __restrict__ h, const int* __restrict__ batch,
    float* __restrict__ pooled, int* __restrict__ gcnt) {
    const int g = blockIdx.x >> 2;
    const int part = blockIdx.x & 3;
    int lo = 0, hi = N_NODES;
    while (lo < hi) { int mid = (lo + hi) >> 1; if (batch[mid] < g) lo = mid + 1; else hi = mid; }
    const int start = lo;
    hi = N_NODES;
    while (lo < hi) { int mid = (lo + hi) >> 1; if (batch[mid] < g + 1) lo = mid + 1; else hi = mid; }
    const int end = lo;

    const int t = threadIdx.x;
    if (part == 0 && t == 0) gcnt[g] = end - start;

    const int c4 = (t & 31) * 4;       // channel group (4 halfs = 8 B)
    const int rg = t >> 5;             // 0..7 row group
    float4 acc = {0.f, 0.f, 0.f, 0.f};
    for (int n = start + part * 8 + rg; n < end; n += 8 * POOL_PARTS) {
        const __half2* p = (const __half2*)(h + (size_t)n * 128 + c4);
        float2 f0 = __half22float2(p[0]);
        float2 f1 = __half22float2(p[1]);
        acc.x += f0.x; acc.y += f0.y; acc.z += f1.x; acc.w += f1.y;
    }
    __shared__ float sm[8][132];
    sm[rg][c4 + 0] = acc.x;
    sm[rg][c4 + 1] = acc.y;
    sm[rg][c4 + 2] = acc.z;
    sm[rg][c4 + 3] = acc.w;
    __syncthreads();
    if (t < 128) {
        float s = 0.f;
#pragma unroll
        for (int r = 0; r < 8; ++r) s += sm[r][t];
        atomicAdd(&pooled[g * 128 + t], s);
    }
}

// ---------------- final linear: out[g][j] = blin[j] + sum_c (pooled[g][c]/cnt) * Wlin[j][c]
__global__ void final_kernel(const float* __restrict__ pooled, const int* __restrict__ gcnt,
                             const float* __restrict__ Wlin, const float* __restrict__ blin,
                             float* __restrict__ out) {
    int g = blockIdx.x;
    int j = threadIdx.x;               // 0..31
    float inv = 1.0f / fmaxf((float)gcnt[g], 1.0f);
    float sum = blin[j];
    const float* prow = pooled + g * 128;
    const float* wrow = Wlin + j * 128;
    for (int c = 0; c < 128; ++c) sum += prow[c] * inv * wrow[c];
    out[g * 32 + j] = sum;
}

extern "C" void kernel_launch(void* const* d_in, const int* in_sizes, int n_in,
                              void* d_out, int out_size, void* d_ws, size_t ws_size,
                              hipStream_t stream) {
    const float* x    = (const float*)d_in[0];
    const int*   src  = (const int*)d_in[1];
    const int*   dst  = ((const int*)d_in[1]) + N_EDGES;
    const int*   batch= (const int*)d_in[2];
    const float* W1l  = (const float*)d_in[3];
    const float* b1   = (const float*)d_in[4];
    const float* W1r  = (const float*)d_in[5];
    const float* W2l  = (const float*)d_in[6];
    const float* b2   = (const float*)d_in[7];
    const float* W2r  = (const float*)d_in[8];
    const float* Wlin = (const float*)d_in[9];
    const float* blin = (const float*)d_in[10];
    float* out = (float*)d_out;

    // all fp16 buffers sized/placed to keep 16B alignment
    __half* xh     = (__half*)d_ws;            // 6,400,000 h (fp16 x)
    __half* mean16 = xh + 6400000;             // 6,400,000 h
    __half* h1_16  = mean16 + 6400000;         // 6,400,000 h
    __half* h2_16  = h1_16 + 6400000;          // 6,400,000 h
    __half* Wh1    = h2_16 + 6400000;          // 32,768 h
    __half* Wl1    = Wh1 + 32768;
    __half* Wh2    = Wl1 + 32768;
    __half* Wl2    = Wh2 + 32768;
    float* pooled  = (float*)(Wl2 + 32768);    // 8,192 f
    int*   gcnt    = (int*)(pooled + N_GRAPHS * 128); // 64 i
    float* invdeg  = (float*)(gcnt + 64);      // 50,000 f
    int*   degi    = (int*)(invdeg + N_NODES); // 50,000 i (adjacent to cursor: one memset)
    int*   cursor  = degi + N_NODES;           // 50,000 i
    int*   rowptr  = cursor + N_NODES;         // 50,001 i
    int*   eidx    = rowptr + N_NODES + 1;     // 600,000 i
    int*   bsum    = eidx + N_EDGES;           // 196 i
    int*   boff    = bsum + N_SCAN_BLOCKS;     // 196 i

    // zero accumulated-into scratch (ws is re-poisoned before every call)
    hipMemsetAsync(degi, 0, (size_t)(2 * N_NODES) * sizeof(int), stream);  // degi+cursor
    hipMemsetAsync(pooled, 0, (size_t)(N_GRAPHS * 128) * sizeof(float), stream);

    // weight prep + fp16 cast of x (independent of CSR build)
    build_w_f16<<<128, 256, 0, stream>>>(W1l, W1r, Wh1, Wl1);
    build_w_f16<<<128, 256, 0, stream>>>(W2l, W2r, Wh2, Wl2);
    cast_f16<<<(N_NODES * 128 / 4 + 255) / 256, 256, 0, stream>>>(x, xh, N_NODES * 128);

    // CSR build: coalesced 3-phase scan
    deg_kernel<<<(N_EDGES + 255) / 256, 256, 0, stream>>>(dst, degi, N_EDGES);
    scan_blocksum<<<N_SCAN_BLOCKS, SCAN_BLK, 0, stream>>>(degi, bsum);
    scan_boff<<<1, 256, 0, stream>>>(bsum, boff, rowptr);
    scan_emit<<<N_SCAN_BLOCKS, SCAN_BLK, 0, stream>>>(degi, boff, rowptr, invdeg);
    fill_kernel<<<(N_EDGES + 255) / 256, 256, 0, stream>>>(src, dst, rowptr, cursor, eidx, N_EDGES);

    const int gemm_grid = (N_NODES + GBM - 1) / GBM;   // 782

    // layer 1: fp16 gather -> fp16 mean -> f16-MFMA GEMM -> fp16 h1
    aggregate_f16<<<(N_NODES + 3) / 4, 256, 0, stream>>>(xh, rowptr, eidx, invdeg, mean16);
    sage_gemm_f16<<<gemm_grid, 256, 0, stream>>>(mean16, xh, Wh1, Wl1, b1, h1_16, N_NODES);

    // layer 2
    aggregate_f16<<<(N_NODES + 3) / 4, 256, 0, stream>>>(h1_16, rowptr, eidx, invdeg, mean16);
    sage_gemm_f16<<<gemm_grid, 256, 0, stream>>>(mean16, h1_16, Wh2, Wl2, b2, h2_16, N_NODES);

    // pool + final linear
    pool_graph<<<N_GRAPHS * POOL_PARTS, 256, 0, stream>>>(h2_16, batch, pooled, gcnt);
    final_kernel<<<N_GRAPHS, 32, 0, stream>>>(pooled, gcnt, Wlin, blin, out);
}

// Round 9
// 263.845 us; speedup vs baseline: 1.3163x; 1.0322x over previous
//
#include <hip/hip_runtime.h>
#include <hip/hip_fp16.h>

#define N_NODES 50000
#define N_EDGES 600000
#define N_GRAPHS 64
#define HID 128
#define OUT_C 32

#define SCAN_BLK 256
#define N_SCAN_BLOCKS ((N_NODES + SCAN_BLK - 1) / SCAN_BLK)   // 196

typedef __attribute__((ext_vector_type(8))) _Float16 half8;
typedef __attribute__((ext_vector_type(4))) _Float16 half4;
typedef __attribute__((ext_vector_type(4))) float f32x4;

// ---------------- fused prep: W1/W2 -> fp16 n-major Wt (k<128: Wl, else Wr), x -> fp16
__global__ __launch_bounds__(256) void prep_kernel(
    const float* __restrict__ x,
    const float* __restrict__ W1l, const float* __restrict__ W1r,
    const float* __restrict__ W2l, const float* __restrict__ W2r,
    __half* __restrict__ xh, __half* __restrict__ Wt1, __half* __restrict__ Wt2) {
    int b = blockIdx.x;
    if (b < 16) {
        int idx = b * 256 + threadIdx.x;            // 0..4095
        for (int i = idx; i < 65536; i += 4096) {
            int which = i >> 15;                    // 0: layer1, 1: layer2
            int j = i & 32767;
            int n = j >> 8, k = j & 255;
            const float* Wl = which ? W2l : W1l;
            const float* Wr = which ? W2r : W1r;
            float a = (k < 128) ? Wl[n * 128 + k] : Wr[n * 128 + (k - 128)];
            (which ? Wt2 : Wt1)[j] = __float2half(a);
        }
    } else {
        int i = ((b - 16) * 256 + threadIdx.x) * 4;
        if (i < N_NODES * 128) {
            float4 v = *(const float4*)(x + i);
            __half2 a = __floats2half2_rn(v.x, v.y);
            __half2 b2 = __floats2half2_rn(v.z, v.w);
            uint2 st;
            st.x = *(const unsigned int*)&a;
            st.y = *(const unsigned int*)&b2;
            *(uint2*)(xh + i) = st;
        }
    }
}

// ---------------- CSR build
__global__ void deg_kernel(const int* __restrict__ dst, int* __restrict__ deg, int E) {
    int e = blockIdx.x * 256 + threadIdx.x;
    if (e < E) atomicAdd(&deg[dst[e]], 1);
}

__global__ __launch_bounds__(SCAN_BLK) void scan_blocksum(
    const int* __restrict__ deg, int* __restrict__ bsum) {
    __shared__ int s[SCAN_BLK];
    int i = blockIdx.x * SCAN_BLK + threadIdx.x;
    s[threadIdx.x] = (i < N_NODES) ? deg[i] : 0;
    __syncthreads();
    for (int off = SCAN_BLK / 2; off > 0; off >>= 1) {
        if (threadIdx.x < off) s[threadIdx.x] += s[threadIdx.x + off];
        __syncthreads();
    }
    if (threadIdx.x == 0) bsum[blockIdx.x] = s[0];
}

__global__ __launch_bounds__(256) void scan_boff(
    const int* __restrict__ bsum, int* __restrict__ boff, int* __restrict__ rowptr) {
    __shared__ int s[256];
    int t = threadIdx.x;
    int v = (t < N_SCAN_BLOCKS) ? bsum[t] : 0;
    s[t] = v;
    __syncthreads();
    for (int off = 1; off < 256; off <<= 1) {
        int u = (t >= off) ? s[t - off] : 0;
        __syncthreads();
        s[t] += u;
        __syncthreads();
    }
    if (t < N_SCAN_BLOCKS) boff[t] = s[t] - v;
    if (t == N_SCAN_BLOCKS - 1) rowptr[N_NODES] = s[t];
}

__global__ __launch_bounds__(SCAN_BLK) void scan_emit(
    const int* __restrict__ deg, const int* __restrict__ boff,
    int* __restrict__ rowptr, float* __restrict__ invdeg) {
    __shared__ int s[SCAN_BLK];
    int i = blockIdx.x * SCAN_BLK + threadIdx.x;
    int t = threadIdx.x;
    int v = (i < N_NODES) ? deg[i] : 0;
    s[t] = v;
    __syncthreads();
    for (int off = 1; off < SCAN_BLK; off <<= 1) {
        int u = (t >= off) ? s[t - off] : 0;
        __syncthreads();
        s[t] += u;
        __syncthreads();
    }
    if (i < N_NODES) {
        rowptr[i] = boff[blockIdx.x] + s[t] - v;
        invdeg[i] = 1.0f / fmaxf((float)v, 1.0f);
    }
}

__global__ void fill_kernel(const int* __restrict__ src, const int* __restrict__ dst,
                            const int* __restrict__ rowptr, int* __restrict__ cursor,
                            int* __restrict__ eidx, int E) {
    int e = blockIdx.x * 256 + threadIdx.x;
    if (e < E) {
        int d = dst[e];
        int pos = atomicAdd(&cursor[d], 1);
        eidx[rowptr[d] + pos] = src[e];
    }
}

// ---------------- fp16 gather-aggregate: 2 nodes per wave, 32 lanes x 8 B per row.
// One VMEM instr gathers 2 edges (512 B). 8/4/2/1 unroll for MLP.
#define AGG_ACC(vv, aa) { aa.x += (float)vv[0]; aa.y += (float)vv[1]; \
                          aa.z += (float)vv[2]; aa.w += (float)vv[3]; }

__global__ __launch_bounds__(256) void aggregate_f16(
    const __half* __restrict__ feat16, const int* __restrict__ rowptr,
    const int* __restrict__ eidx, const float* __restrict__ invdeg,
    __half* __restrict__ mean16) {
    const int wave = threadIdx.x >> 6;
    const int lane = threadIdx.x & 63;
    const int nh   = lane >> 5;          // which of the wave's 2 nodes
    const int sub  = lane & 31;          // 32 lanes x 4 halfs = 128 ch
    const int node = blockIdx.x * 8 + wave * 2 + nh;
    const bool act = (node < N_NODES);
    int beg = 0, end = 0;
    if (act) { beg = rowptr[node]; end = rowptr[node + 1]; }
    const size_t coff = (size_t)sub * 4;

    float4 a0 = {0.f,0.f,0.f,0.f}, a1 = {0.f,0.f,0.f,0.f};
    float4 a2 = {0.f,0.f,0.f,0.f}, a3 = {0.f,0.f,0.f,0.f};
    int i = beg;
    for (; i + 8 <= end; i += 8) {
        int s0 = eidx[i+0], s1 = eidx[i+1], s2 = eidx[i+2], s3 = eidx[i+3];
        int s4 = eidx[i+4], s5 = eidx[i+5], s6 = eidx[i+6], s7 = eidx[i+7];
        half4 v0 = *(const half4*)(feat16 + (size_t)s0 * 128 + coff);
        half4 v1 = *(const half4*)(feat16 + (size_t)s1 * 128 + coff);
        half4 v2 = *(const half4*)(feat16 + (size_t)s2 * 128 + coff);
        half4 v3 = *(const half4*)(feat16 + (size_t)s3 * 128 + coff);
        half4 v4 = *(const half4*)(feat16 + (size_t)s4 * 128 + coff);
        half4 v5 = *(const half4*)(feat16 + (size_t)s5 * 128 + coff);
        half4 v6 = *(const half4*)(feat16 + (size_t)s6 * 128 + coff);
        half4 v7 = *(const half4*)(feat16 + (size_t)s7 * 128 + coff);
        AGG_ACC(v0, a0); AGG_ACC(v1, a1); AGG_ACC(v2, a2); AGG_ACC(v3, a3);
        AGG_ACC(v4, a0); AGG_ACC(v5, a1); AGG_ACC(v6, a2); AGG_ACC(v7, a3);
    }
    if (i + 4 <= end) {
        int s0 = eidx[i+0], s1 = eidx[i+1], s2 = eidx[i+2], s3 = eidx[i+3];
        half4 v0 = *(const half4*)(feat16 + (size_t)s0 * 128 + coff);
        half4 v1 = *(const half4*)(feat16 + (size_t)s1 * 128 + coff);
        half4 v2 = *(const half4*)(feat16 + (size_t)s2 * 128 + coff);
        half4 v3 = *(const half4*)(feat16 + (size_t)s3 * 128 + coff);
        AGG_ACC(v0, a0); AGG_ACC(v1, a1); AGG_ACC(v2, a2); AGG_ACC(v3, a3);
        i += 4;
    }
    if (i + 2 <= end) {
        int s0 = eidx[i+0], s1 = eidx[i+1];
        half4 v0 = *(const half4*)(feat16 + (size_t)s0 * 128 + coff);
        half4 v1 = *(const half4*)(feat16 + (size_t)s1 * 128 + coff);
        AGG_ACC(v0, a0); AGG_ACC(v1, a1);
        i += 2;
    }
    if (i < end) {
        int s0 = eidx[i];
        half4 v0 = *(const half4*)(feat16 + (size_t)s0 * 128 + coff);
        AGG_ACC(v0, a0);
    }

    if (act) {
        const float sc = invdeg[node];
        half4 r;
        r[0] = (_Float16)(((a0.x + a1.x) + (a2.x + a3.x)) * sc);
        r[1] = (_Float16)(((a0.y + a1.y) + (a2.y + a3.y)) * sc);
        r[2] = (_Float16)(((a0.z + a1.z) + (a2.z + a3.z)) * sc);
        r[3] = (_Float16)(((a0.w + a1.w) + (a2.w + a3.w)) * sc);
        *(half4*)(mean16 + (size_t)node * 128 + coff) = r;
    }
}

// ---------------- fp16 MFMA SAGE GEMM (M=50000, N=128, K=256)
// Single fp16 B plane staged ONCE into LDS (64 KB + pad); A fragments in regs;
// K-loop: 64 ds_read_b128 + 64 MFMA, one barrier total.
#define GBM 64
#define BPAD 8   // 16 B pad per row -> adjacent-row bank shift of 4, 2-way max (free)

__global__ __launch_bounds__(256) void sage_gemm_f16(
    const __half* __restrict__ mean16, const __half* __restrict__ feat16,
    const __half* __restrict__ Wt, const float* __restrict__ bias,
    __half* __restrict__ out16, int M) {
    __shared__ __align__(16) __half Bs[128][256 + BPAD];

    const int tid = threadIdx.x;
    const int wave = tid >> 6;
    const int lane = tid & 63;
    const int l15 = lane & 15;
    const int quad = lane >> 4;
    const int row0 = blockIdx.x * GBM;
    const int gi_a = min(row0 + wave * 16 + l15, M - 1);   // clamp OOB (stores guarded)

    // stage all of B: 128 rows x 32 half8
    for (int id = tid; id < 128 * 32; id += 256) {
        int n = id >> 5;
        int kc = (id & 31) * 8;
        *(half8*)&Bs[n][kc] = *(const half8*)(Wt + (size_t)n * 256 + kc);
    }

    // prefetch all 8 A fragments (16 B each, coalesced across l15)
    half8 af[8];
#pragma unroll
    for (int kb = 0; kb < 8; ++kb) {
        const int k0 = kb * 32;
        const __half* ap = (k0 < 128)
            ? (mean16 + (size_t)gi_a * 128 + k0 + quad * 8)
            : (feat16 + (size_t)gi_a * 128 + (k0 - 128) + quad * 8);
        af[kb] = *(const half8*)ap;
    }

    f32x4 acc[8];
#pragma unroll
    for (int t = 0; t < 8; ++t) acc[t] = (f32x4){0.f, 0.f, 0.f, 0.f};

    __syncthreads();

#pragma unroll
    for (int kb = 0; kb < 8; ++kb) {
#pragma unroll
        for (int t = 0; t < 8; ++t) {
            const half8 b = *(const half8*)&Bs[t * 16 + l15][kb * 32 + quad * 8];
            acc[t] = __builtin_amdgcn_mfma_f32_16x16x32_f16(af[kb], b, acc[t], 0, 0, 0);
        }
    }

    // epilogue: row = row0 + wave*16 + quad*4 + r, col = t*16 + l15
#pragma unroll
    for (int r = 0; r < 4; ++r) {
        int gi = row0 + wave * 16 + quad * 4 + r;
        if (gi < M) {
#pragma unroll
            for (int t = 0; t < 8; ++t) {
                int col = t * 16 + l15;
                float v = fmaxf(acc[t][r] + bias[col], 0.f);
                out16[(size_t)gi * 128 + col] = __float2half(v);
            }
        }
    }
}

// ---------------- pooling: 4 blocks per graph, coalesced strided fp16 reads,
// LDS reduce, one atomicAdd per channel per block. batch is sorted.
#define POOL_PARTS 4
__global__ __launch_bounds__(256) void pool_graph(
    const __half* __restrict__ h, const int* __restrict__ batch,
    float* __restrict__ pooled, int* __restrict__ gcnt) {
    const int g = blockIdx.x >> 2;
    const int part = blockIdx.x & 3;
    int lo = 0, hi = N_NODES;
    while (lo < hi) { int mid = (lo + hi) >> 1; if (batch[mid] < g) lo = mid + 1; else hi = mid; }
    const int start = lo;
    hi = N_NODES;
    while (lo < hi) { int mid = (lo + hi) >> 1; if (batch[mid] < g + 1) lo = mid + 1; else hi = mid; }
    const int end = lo;

    const int t = threadIdx.x;
    if (part == 0 && t == 0) gcnt[g] = end - start;

    const int c4 = (t & 31) * 4;       // channel group (4 halfs = 8 B)
    const int rg = t >> 5;             // 0..7 row group
    float4 acc = {0.f, 0.f, 0.f, 0.f};
    for (int n = start + part * 8 + rg; n < end; n += 8 * POOL_PARTS) {
        const __half2* p = (const __half2*)(h + (size_t)n * 128 + c4);
        float2 f0 = __half22float2(p[0]);
        float2 f1 = __half22float2(p[1]);
        acc.x += f0.x; acc.y += f0.y; acc.z += f1.x; acc.w += f1.y;
    }
    __shared__ float sm[8][132];
    sm[rg][c4 + 0] = acc.x;
    sm[rg][c4 + 1] = acc.y;
    sm[rg][c4 + 2] = acc.z;
    sm[rg][c4 + 3] = acc.w;
    __syncthreads();
    if (t < 128) {
        float s = 0.f;
#pragma unroll
        for (int r = 0; r < 8; ++r) s += sm[r][t];
        atomicAdd(&pooled[g * 128 + t], s);
    }
}

// ---------------- final linear
__global__ void final_kernel(const float* __restrict__ pooled, const int* __restrict__ gcnt,
                             const float* __restrict__ Wlin, const float* __restrict__ blin,
                             float* __restrict__ out) {
    int g = blockIdx.x;
    int j = threadIdx.x;               // 0..31
    float inv = 1.0f / fmaxf((float)gcnt[g], 1.0f);
    float sum = blin[j];
    const float* prow = pooled + g * 128;
    const float* wrow = Wlin + j * 128;
    for (int c = 0; c < 128; ++c) sum += prow[c] * inv * wrow[c];
    out[g * 32 + j] = sum;
}

extern "C" void kernel_launch(void* const* d_in, const int* in_sizes, int n_in,
                              void* d_out, int out_size, void* d_ws, size_t ws_size,
                              hipStream_t stream) {
    const float* x    = (const float*)d_in[0];
    const int*   src  = (const int*)d_in[1];
    const int*   dst  = ((const int*)d_in[1]) + N_EDGES;
    const int*   batch= (const int*)d_in[2];
    const float* W1l  = (const float*)d_in[3];
    const float* b1   = (const float*)d_in[4];
    const float* W1r  = (const float*)d_in[5];
    const float* W2l  = (const float*)d_in[6];
    const float* b2   = (const float*)d_in[7];
    const float* W2r  = (const float*)d_in[8];
    const float* Wlin = (const float*)d_in[9];
    const float* blin = (const float*)d_in[10];
    float* out = (float*)d_out;

    __half* xh     = (__half*)d_ws;            // 6,400,000 h (fp16 x)
    __half* mean16 = xh + 6400000;             // 6,400,000 h
    __half* h1_16  = mean16 + 6400000;         // 6,400,000 h
    __half* h2_16  = h1_16 + 6400000;          // 6,400,000 h
    __half* Wt1    = h2_16 + 6400000;          // 32,768 h
    __half* Wt2    = Wt1 + 32768;              // 32,768 h
    float* pooled  = (float*)(Wt2 + 32768);    // 8,192 f
    int*   gcnt    = (int*)(pooled + N_GRAPHS * 128); // 64 i
    float* invdeg  = (float*)(gcnt + 64);      // 50,000 f
    int*   degi    = (int*)(invdeg + N_NODES); // 50,000 i (adjacent to cursor: one memset)
    int*   cursor  = degi + N_NODES;           // 50,000 i
    int*   rowptr  = cursor + N_NODES;         // 50,001 i
    int*   eidx    = rowptr + N_NODES + 1;     // 600,000 i
    int*   bsum    = eidx + N_EDGES;           // 196 i
    int*   boff    = bsum + N_SCAN_BLOCKS;     // 196 i

    // zero accumulated-into scratch (ws is re-poisoned before every call)
    hipMemsetAsync(degi, 0, (size_t)(2 * N_NODES) * sizeof(int), stream);  // degi+cursor
    hipMemsetAsync(pooled, 0, (size_t)(N_GRAPHS * 128) * sizeof(float), stream);

    // fused prep: weights -> fp16 n-major, x -> fp16
    prep_kernel<<<16 + (N_NODES * 128 / 4 + 255) / 256, 256, 0, stream>>>(
        x, W1l, W1r, W2l, W2r, xh, Wt1, Wt2);

    // CSR build: coalesced 3-phase scan
    deg_kernel<<<(N_EDGES + 255) / 256, 256, 0, stream>>>(dst, degi, N_EDGES);
    scan_blocksum<<<N_SCAN_BLOCKS, SCAN_BLK, 0, stream>>>(degi, bsum);
    scan_boff<<<1, 256, 0, stream>>>(bsum, boff, rowptr);
    scan_emit<<<N_SCAN_BLOCKS, SCAN_BLK, 0, stream>>>(degi, boff, rowptr, invdeg);
    fill_kernel<<<(N_EDGES + 255) / 256, 256, 0, stream>>>(src, dst, rowptr, cursor, eidx, N_EDGES);

    const int gemm_grid = (N_NODES + GBM - 1) / GBM;   // 782
    const int agg_grid = (N_NODES + 7) / 8;            // 6250

    // layer 1
    aggregate_f16<<<agg_grid, 256, 0, stream>>>(xh, rowptr, eidx, invdeg, mean16);
    sage_gemm_f16<<<gemm_grid, 256, 0, stream>>>(mean16, xh, Wt1, b1, h1_16, N_NODES);

    // layer 2
    aggregate_f16<<<agg_grid, 256, 0, stream>>>(h1_16, rowptr, eidx, invdeg, mean16);
    sage_gemm_f16<<<gemm_grid, 256, 0, stream>>>(mean16, h1_16, Wt2, b2, h2_16, N_NODES);

    // pool + final linear
    pool_graph<<<N_GRAPHS * POOL_PARTS, 256, 0, stream>>>(h2_16, batch, pooled, gcnt);
    final_kernel<<<N_GRAPHS, 32, 0, stream>>>(pooled, gcnt, Wlin, blin, out);
}